// Round 2
// baseline (86.307 us; speedup 1.0000x reference)
//
#include <hip/hip_runtime.h>
#include <math.h>

#define NIMG 64
#define HW   1024
#define NCH  85
#define NCLS 80
#define CQ   20          // classes per NMS block (4 blocks per image)
#define CONF_TH 0.25f
#define NMS_TH  0.35f

__device__ __forceinline__ float fast_tanh(float x) {
  float e = __expf(2.0f * x);
  return 1.0f - 2.0f * __builtin_amdgcn_rcpf(e + 1.0f);
}
__device__ __forceinline__ float fast_sigmoid(float x) {
  return __builtin_amdgcn_rcpf(1.0f + __expf(-x));
}

// ---------------------------------------------------------------------------
// Decode kernel: one thread per pixel, 256 blocks x 256 threads (all 256 CUs).
// Consecutive lanes hit consecutive pixels -> fully-coalesced 256B wave loads.
// 4 independent 20-class argmax chains; ascending-chain merge with strict '>'
// == exact first-occurrence argmax. Also zeroes keepOut (1 store/thread) so
// the NMS kernel only writes the kept 1.0s.
// ---------------------------------------------------------------------------
__global__ __launch_bounds__(256) void decode_kernel(const float* __restrict__ preds,
                                                     float* __restrict__ out,
                                                     float* __restrict__ keepOut) {
  int gid = blockIdx.x * 256 + threadIdx.x;   // 0 .. 65535
  int n = gid >> 10;
  int t = gid & 1023;
  const float* bp = preds + (size_t)n * (NCH * HW) + t;

  float pobj = bp[0];
  float tx = bp[(size_t)1 * HW];
  float ty = bp[(size_t)2 * HW];
  float tw = bp[(size_t)3 * HW];
  float th = bp[(size_t)4 * HW];

  float b0, b1, b2, b3;
  int i0, i1, i2, i3;
  b0 = bp[(size_t)(5 +  0) * HW]; i0 =  0;
  b1 = bp[(size_t)(5 + 20) * HW]; i1 = 20;
  b2 = bp[(size_t)(5 + 40) * HW]; i2 = 40;
  b3 = bp[(size_t)(5 + 60) * HW]; i3 = 60;
#pragma unroll
  for (int c = 1; c < 20; ++c) {
    float v0 = bp[(size_t)(5 +  0 + c) * HW];
    float v1 = bp[(size_t)(5 + 20 + c) * HW];
    float v2 = bp[(size_t)(5 + 40 + c) * HW];
    float v3 = bp[(size_t)(5 + 60 + c) * HW];
    if (v0 > b0) { b0 = v0; i0 =  0 + c; }
    if (v1 > b1) { b1 = v1; i1 = 20 + c; }
    if (v2 > b2) { b2 = v2; i2 = 40 + c; }
    if (v3 > b3) { b3 = v3; i3 = 60 + c; }
  }
  float best = b0; int bc = i0;
  if (b1 > best) { best = b1; bc = i1; }
  if (b2 > best) { best = b2; bc = i2; }
  if (b3 > best) { best = b3; bc = i3; }

  float score = pobj * best;                 // bit-exact vs reference

  float gx = (float)(t & 31);
  float gy = (float)(t >> 5);
  float bcx = (fast_tanh(tx) + gx) * 0.03125f;
  float bcy = (fast_tanh(ty) + gy) * 0.03125f;
  float bw = fast_sigmoid(tw);
  float bh = fast_sigmoid(th);

  float x1 = bcx - 0.5f * bw, y1 = bcy - 0.5f * bh;
  float x2 = bcx + 0.5f * bw, y2 = bcy + 0.5f * bh;

  float2* ob = (float2*)(out + (size_t)gid * 6);
  ob[0] = make_float2(x1, y1);
  ob[1] = make_float2(x2, y2);
  ob[2] = make_float2(score, (float)bc);

  keepOut[gid] = 0.0f;
}

// ---------------------------------------------------------------------------
// NMS kernel: 256 blocks x 256 threads — block = (image n, class quarter cq).
// Classes are independent, so per-class rank + suppression + greedy scan is
// exactly the previously-verified logic; this version just runs 4 class
// quarters of each image on 4 different CUs (full machine, 4-wave barriers).
// Boxes re-read from `out` are L2-hot (1.8 MB total, 4x redundancy ~ 7 MB).
// ---------------------------------------------------------------------------
__global__ __launch_bounds__(256) void nms_kernel(const float* __restrict__ boxes,
                                                  float* __restrict__ keepOut) {
  int n  = blockIdx.x >> 2;
  int c0 = (blockIdx.x & 3) * CQ;            // classes c0 .. c0+CQ-1
  int t = threadIdx.x;

  __shared__ float sx1[HW], sy1[HW], sx2[HW], sy2[HW], sarea[HW], sscore[HW];
  __shared__ int bucket[HW];                 // unordered class members
  __shared__ int sorted[HW];                 // (score desc, idx asc) order
  __shared__ unsigned long long supp[HW];    // suppression bits vs lower ranks
  __shared__ int cnt[CQ], offs[CQ], start[CQ];

  if (t < CQ) cnt[t] = 0;

  // ---- load this image's decoded boxes: 4 pixels per thread, coalesced ----
  float px1[4], py1[4], px2[4], py2[4], par[4], psc[4];
  int pcl[4]; bool pval[4];
#pragma unroll
  for (int k = 0; k < 4; ++k) {
    int p = t + 256 * k;
    const float2* ib = (const float2*)(boxes + ((size_t)n * HW + p) * 6);
    float2 a01 = ib[0];
    float2 a23 = ib[1];
    float2 a45 = ib[2];
    px1[k] = a01.x; py1[k] = a01.y; px2[k] = a23.x; py2[k] = a23.y;
    psc[k] = a45.x;
    int cl = (int)a45.y;
    pcl[k] = cl;
    par[k] = (px2[k] - px1[k]) * (py2[k] - py1[k]);
    sx1[p] = px1[k]; sy1[p] = py1[k]; sx2[p] = px2[k]; sy2[p] = py2[k];
    sarea[p] = par[k];
    sscore[p] = psc[k];
    pval[k] = (psc[k] > CONF_TH) && (cl >= c0) && (cl < c0 + CQ);
  }
  __syncthreads();

  // ---- count valid per class (cnt[] init is barrier-protected above) ----
#pragma unroll
  for (int k = 0; k < 4; ++k)
    if (pval[k]) atomicAdd(&cnt[pcl[k] - c0], 1);
  __syncthreads();

  // ---- exclusive prefix sum over CQ=20 class counts (wave-0 shfl scan) ----
  if (t < 64) {
    int c = (t < CQ) ? cnt[t] : 0;
    int x = c;
#pragma unroll
    for (int d = 1; d < 32; d <<= 1) {
      int y = __shfl_up(x, d, 64);
      if (t >= d) x += y;
    }
    if (t < CQ) { start[t] = x - c; offs[t] = x - c; }
  }
  __syncthreads();

  // ---- scatter valid boxes to class buckets (order irrelevant) ----
#pragma unroll
  for (int k = 0; k < 4; ++k)
    if (pval[k]) {
      int p = atomicAdd(&offs[pcl[k] - c0], 1);
      bucket[p] = t + 256 * k;
    }
  __syncthreads();

  // ---- parallel rank within class = exact stable-argsort position ----
  int rk[4];
#pragma unroll
  for (int k = 0; k < 4; ++k)
    if (pval[k]) {
      int p = t + 256 * k;
      int cl = pcl[k] - c0;
      int s0 = start[cl], m = cnt[cl];
      float sc = psc[k];
      int r = 0;
      for (int j = 0; j < m; ++j) {
        int jb = bucket[s0 + j];
        float sj = sscore[jb];
        r += (sj > sc) || (sj == sc && jb < p);
      }
      rk[k] = r;
      sorted[s0 + r] = p;
    }
  __syncthreads();

  // ---- parallel suppression bitmasks vs all lower-rank members ----
#pragma unroll
  for (int k = 0; k < 4; ++k)
    if (pval[k]) {
      int cl = pcl[k] - c0;
      int s0 = start[cl];
      int a = rk[k];
      int lim = a < 64 ? a : 64;
      unsigned long long mask = 0ull;
      for (int b = 0; b < lim; ++b) {
        int jb = sorted[s0 + b];
        float iw = fminf(px2[k], sx2[jb]) - fmaxf(px1[k], sx1[jb]);
        float ih = fminf(py2[k], sy2[jb]) - fmaxf(py1[k], sy1[jb]);
        iw = fmaxf(iw, 0.0f);
        ih = fmaxf(ih, 0.0f);
        float inter = iw * ih;
        float iou = inter / (par[k] + sarea[jb] - inter + 1e-9f);  // exact ref op order
        if (iou > NMS_TH) mask |= (1ull << b);
      }
      supp[s0 + a] = mask;
    }
  __syncthreads();

  // ---- serial greedy scan per class: O(m) register bit-ops ----
  if (t < CQ) {
    int m = cnt[t], s0 = start[t];
    if (m <= 64) {
      unsigned long long kept = 0ull;
      for (int a = 0; a < m; ++a) {
        unsigned long long sa = supp[s0 + a];
        if ((sa & kept) == 0ull) {
          kept |= (1ull << a);
          keepOut[(size_t)n * HW + sorted[s0 + a]] = 1.0f;
        }
      }
    } else {
      // never expected (Poisson mean ~6/class); exact O(m^2) fallback
      for (int a = 0; a < m; ++a) {
        int ia = sorted[s0 + a];
        float ax1 = sx1[ia], ay1 = sy1[ia], ax2 = sx2[ia], ay2 = sy2[ia];
        float ar2 = sarea[ia];
        bool kp = true;
        for (int b = 0; b < a; ++b) {
          if (!bucket[s0 + b]) continue;   // bucket reused as kept-flags
          int jb = sorted[s0 + b];
          float iw = fminf(ax2, sx2[jb]) - fmaxf(ax1, sx1[jb]);
          float ih = fminf(ay2, sy2[jb]) - fmaxf(ay1, sy1[jb]);
          iw = fmaxf(iw, 0.0f);
          ih = fmaxf(ih, 0.0f);
          float inter = iw * ih;
          float iou = inter / (ar2 + sarea[jb] - inter + 1e-9f);
          if (iou > NMS_TH) { kp = false; break; }
        }
        bucket[s0 + a] = kp ? 1 : 0;
        if (kp) keepOut[(size_t)n * HW + ia] = 1.0f;
      }
    }
  }
}

extern "C" void kernel_launch(void* const* d_in, const int* in_sizes, int n_in,
                              void* d_out, int out_size, void* d_ws, size_t ws_size,
                              hipStream_t stream) {
  const float* preds = (const float*)d_in[0];
  float* out = (float*)d_out;
  float* keepOut = out + (size_t)NIMG * HW * 6;

  decode_kernel<<<NIMG * HW / 256, 256, 0, stream>>>(preds, out, keepOut);
  nms_kernel<<<NIMG * 4, 256, 0, stream>>>(out, keepOut);
}